// Round 1
// baseline (483.077 us; speedup 1.0000x reference)
//
#include <hip/hip_runtime.h>

typedef float f32x4 __attribute__((ext_vector_type(4)));
typedef short bf16x8 __attribute__((ext_vector_type(8)));

__device__ __forceinline__ float bf2f(unsigned short h) {
  return __uint_as_float(((unsigned int)h) << 16);
}
__device__ __forceinline__ unsigned short f2bf(float f) {
  unsigned int u = __float_as_uint(f);
  unsigned int r = u + 0x7fffu + ((u >> 16) & 1u);
  return (unsigned short)(r >> 16);
}

__device__ __forceinline__ void gload_lds16(const void* g, void* l) {
  __builtin_amdgcn_global_load_lds((const __attribute__((address_space(1))) void*)g,
                                   (__attribute__((address_space(3))) void*)l, 16, 0, 0);
}

// ---------------- fp32 -> bf16 elementwise convert (vectorized) ----------------
__global__ void conv_bf16(const float* __restrict__ src, unsigned short* __restrict__ dst, int n4) {
  for (int i = blockIdx.x * blockDim.x + threadIdx.x; i < n4; i += gridDim.x * blockDim.x) {
    float4 v = ((const float4*)src)[i];
    ushort4 o;
    o.x = f2bf(v.x); o.y = f2bf(v.y); o.z = f2bf(v.z); o.w = f2bf(v.w);
    ((ushort4*)dst)[i] = o;
  }
}

// ------------- fp32 [R][C] -> bf16 dst[C + dstRowOff][R] transpose-convert -------------
__global__ void tconv(const float* __restrict__ src, unsigned short* __restrict__ dst,
                      int C, int dstRowOff, int dstLD) {
  __shared__ float tile[32][33];
  int c0 = blockIdx.x * 32, r0 = blockIdx.y * 32;
  int tx = threadIdx.x, ty = threadIdx.y;
#pragma unroll
  for (int i = 0; i < 4; ++i)
    tile[ty + i * 8][tx] = src[(size_t)(r0 + ty + i * 8) * C + c0 + tx];
  __syncthreads();
#pragma unroll
  for (int i = 0; i < 4; ++i)
    dst[(size_t)(dstRowOff + c0 + ty + i * 8) * dstLD + r0 + tx] = f2bf(tile[tx][ty + i * 8]);
}

// ---------------- GEMM: C[M][N] = A[M][K] * BT[N][K]^T, bf16 in, OutT out ----------------
template <typename OutT>
__global__ __launch_bounds__(256) void gemm_bt(const unsigned short* __restrict__ A,
                                               const unsigned short* __restrict__ BT,
                                               OutT* __restrict__ C, int M, int N, int K) {
  __shared__ unsigned short As[128 * 32];
  __shared__ unsigned short Bs[128 * 32];
  const int tid = threadIdx.x;
  const int lane = tid & 63;
  const int wid = tid >> 6;
  const int wr = wid >> 1, wc = wid & 1;
  const int bm = blockIdx.y, bn = blockIdx.x;
  const unsigned short* Ab = A + (size_t)bm * 128 * K;
  const unsigned short* Bb = BT + (size_t)bn * 128 * K;
  f32x4 acc[4][4] = {};
  const int f0 = tid * 8;
  const int row0 = f0 >> 5, col0 = f0 & 31;
  const int f1 = 2048 + tid * 8;
  const int row1 = f1 >> 5, col1 = f1 & 31;
  for (int k0 = 0; k0 < K; k0 += 32) {
    gload_lds16(Ab + (size_t)row0 * K + k0 + col0, &As[wid * 512]);
    gload_lds16(Ab + (size_t)row1 * K + k0 + col1, &As[2048 + wid * 512]);
    gload_lds16(Bb + (size_t)row0 * K + k0 + col0, &Bs[wid * 512]);
    gload_lds16(Bb + (size_t)row1 * K + k0 + col1, &Bs[2048 + wid * 512]);
    __syncthreads();
    bf16x8 af[4], bfr[4];
#pragma unroll
    for (int i = 0; i < 4; ++i) {
      af[i] = *(const bf16x8*)&As[(wr * 64 + i * 16 + (lane & 15)) * 32 + (lane >> 4) * 8];
      bfr[i] = *(const bf16x8*)&Bs[(wc * 64 + i * 16 + (lane & 15)) * 32 + (lane >> 4) * 8];
    }
#pragma unroll
    for (int i = 0; i < 4; ++i)
#pragma unroll
      for (int j = 0; j < 4; ++j)
        acc[i][j] = __builtin_amdgcn_mfma_f32_16x16x32_bf16(af[i], bfr[j], acc[i][j], 0, 0, 0);
    __syncthreads();
  }
  const int rbase = bm * 128 + wr * 64 + ((lane >> 4) << 2);
  const int cbase = bn * 128 + wc * 64 + (lane & 15);
#pragma unroll
  for (int i = 0; i < 4; ++i)
#pragma unroll
    for (int j = 0; j < 4; ++j)
#pragma unroll
      for (int r = 0; r < 4; ++r) {
        int row = rbase + i * 16 + r;
        int col = cbase + j * 16;
        if constexpr (sizeof(OutT) == 2)
          C[(size_t)row * N + col] = f2bf(acc[i][j][r]);
        else
          C[(size_t)row * N + col] = acc[i][j][r];
      }
}

// ---------------- RoPE: qgk cols -> head-major roped q/k ----------------
__global__ void rope_qk(const unsigned short* __restrict__ qgk, const float* __restrict__ cosT,
                        const float* __restrict__ sinT, unsigned short* __restrict__ qrope,
                        unsigned short* __restrict__ krope) {
  int head = blockIdx.y;       // 0..31 q heads, 32..39 kv heads
  int tid = threadIdx.x;       // 256 = 4 rows x 64 dims
  int d = tid & 63;
  int row = blockIdx.x * 4 + (tid >> 6);  // 0..4095  (= b*2048 + s)
  int b = row >> 11, s = row & 2047;
  int base = (head < 32) ? head * 64 : 4096 + (head - 32) * 64;
  size_t off = (size_t)row * 4608 + base;
  float x = bf2f(qgk[off + d]);
  float xp = bf2f(qgk[off + (d ^ 32)]);
  float c = cosT[s * 64 + d], sn = sinT[s * 64 + d];
  float v = x * c + ((d < 32) ? -xp : xp) * sn;
  if (head < 32)
    qrope[((size_t)(b * 32 + head) * 2048 + s) * 64 + d] = f2bf(v);
  else
    krope[((size_t)(b * 8 + (head - 32)) * 2048 + s) * 64 + d] = f2bf(v);
}

// ---------------- krope [bh][2048][64] -> kT [bh][64][2048] ----------------
__global__ void ktrans(const unsigned short* __restrict__ krope, unsigned short* __restrict__ kT) {
  __shared__ unsigned short tile[64][65];
  int bh = blockIdx.y;
  int s0 = blockIdx.x * 64;
  const unsigned short* src = krope + (size_t)bh * 2048 * 64;
  unsigned short* dst = kT + (size_t)bh * 64 * 2048;
  int tx = threadIdx.x & 63, ty = threadIdx.x >> 6;
#pragma unroll
  for (int i = 0; i < 16; ++i)
    tile[ty + i * 4][tx] = src[(size_t)(s0 + ty + i * 4) * 64 + tx];
  __syncthreads();
#pragma unroll
  for (int i = 0; i < 16; ++i)
    dst[(size_t)(ty + i * 4) * 2048 + s0 + tx] = tile[tx][ty + i * 4];
}

// ---------------- fused causal flash attention (V == roped K), gated epilogue ----------------
__global__ __launch_bounds__(256) void attn_fused(const unsigned short* __restrict__ qrope,
                                                  const unsigned short* __restrict__ krope,
                                                  const unsigned short* __restrict__ kT,
                                                  const unsigned short* __restrict__ qgk,
                                                  unsigned short* __restrict__ attng) {
  __shared__ unsigned short Qs[64 * 64];
  __shared__ unsigned short Ks[64 * 64];
  __shared__ unsigned short KTs[64 * 64];
  __shared__ unsigned short Ps[64 * 64];
  const int qblk = blockIdx.x;           // 0..31
  const int bh = blockIdx.y;             // 0..63
  const int b = bh >> 5, h = bh & 31, kh = h >> 2;
  const int q0 = qblk * 64;
  const int tid = threadIdx.x, lane = tid & 63, wid = tid >> 6;
  const unsigned short* Qbase = qrope + ((size_t)(b * 32 + h) * 2048 + q0) * 64;
  const unsigned short* Kbase = krope + (size_t)(b * 8 + kh) * 2048 * 64;
  const unsigned short* KTbase = kT + (size_t)(b * 8 + kh) * 64 * 2048;
  const int f0 = tid * 8, f1 = 2048 + tid * 8;
  const int r0 = f0 >> 6, c0 = f0 & 63;
  const int r1 = f1 >> 6, c1 = f1 & 63;
  gload_lds16(Qbase + (size_t)r0 * 64 + c0, &Qs[wid * 512]);
  gload_lds16(Qbase + (size_t)r1 * 64 + c1, &Qs[2048 + wid * 512]);
  __syncthreads();
  bf16x8 qf[2];
#pragma unroll
  for (int ks = 0; ks < 2; ++ks)
    qf[ks] = *(const bf16x8*)&Qs[(wid * 16 + (lane & 15)) * 64 + ks * 32 + (lane >> 4) * 8];
  f32x4 oacc[4] = {};
  float mrow[4], lrow[4];
#pragma unroll
  for (int r = 0; r < 4; ++r) { mrow[r] = -1e30f; lrow[r] = 0.f; }
  const int ntiles = qblk + 1;
  for (int t = 0; t < ntiles; ++t) {
    __syncthreads();
    gload_lds16(Kbase + ((size_t)t * 64 + r0) * 64 + c0, &Ks[wid * 512]);
    gload_lds16(Kbase + ((size_t)t * 64 + r1) * 64 + c1, &Ks[2048 + wid * 512]);
    gload_lds16(KTbase + (size_t)r0 * 2048 + t * 64 + c0, &KTs[wid * 512]);
    gload_lds16(KTbase + (size_t)r1 * 2048 + t * 64 + c1, &KTs[2048 + wid * 512]);
    __syncthreads();
    f32x4 s[4] = {};
#pragma unroll
    for (int ks = 0; ks < 2; ++ks)
#pragma unroll
      for (int nf = 0; nf < 4; ++nf) {
        bf16x8 kf = *(const bf16x8*)&Ks[(nf * 16 + (lane & 15)) * 64 + ks * 32 + (lane >> 4) * 8];
        s[nf] = __builtin_amdgcn_mfma_f32_16x16x32_bf16(qf[ks], kf, s[nf], 0, 0, 0);
      }
    if (t == qblk) {
#pragma unroll
      for (int nf = 0; nf < 4; ++nf)
#pragma unroll
        for (int r = 0; r < 4; ++r) {
          int kv = nf * 16 + (lane & 15);
          int qr = wid * 16 + ((lane >> 4) << 2) + r;
          if (kv > qr) s[nf][r] += -1e9f;
        }
    }
    float scale[4];
#pragma unroll
    for (int r = 0; r < 4; ++r) {
      float pm = fmaxf(fmaxf(s[0][r], s[1][r]), fmaxf(s[2][r], s[3][r]));
#pragma unroll
      for (int msk = 1; msk < 16; msk <<= 1) pm = fmaxf(pm, __shfl_xor(pm, msk, 64));
      float mnew = fmaxf(mrow[r], pm);
      scale[r] = __expf(mrow[r] - mnew);
      mrow[r] = mnew;
    }
    float rs[4] = {0.f, 0.f, 0.f, 0.f};
#pragma unroll
    for (int nf = 0; nf < 4; ++nf)
#pragma unroll
      for (int r = 0; r < 4; ++r) {
        float p = __expf(s[nf][r] - mrow[r]);
        s[nf][r] = p;
        rs[r] += p;
      }
#pragma unroll
    for (int r = 0; r < 4; ++r) {
#pragma unroll
      for (int msk = 1; msk < 16; msk <<= 1) rs[r] += __shfl_xor(rs[r], msk, 64);
      lrow[r] = lrow[r] * scale[r] + rs[r];
#pragma unroll
      for (int df = 0; df < 4; ++df) oacc[df][r] *= scale[r];
    }
#pragma unroll
    for (int nf = 0; nf < 4; ++nf)
#pragma unroll
      for (int r = 0; r < 4; ++r)
        Ps[(wid * 16 + ((lane >> 4) << 2) + r) * 64 + nf * 16 + (lane & 15)] = f2bf(s[nf][r]);
    __syncthreads();
#pragma unroll
    for (int ks = 0; ks < 2; ++ks) {
      bf16x8 pf = *(const bf16x8*)&Ps[(wid * 16 + (lane & 15)) * 64 + ks * 32 + (lane >> 4) * 8];
#pragma unroll
      for (int df = 0; df < 4; ++df) {
        bf16x8 vf = *(const bf16x8*)&KTs[(df * 16 + (lane & 15)) * 64 + ks * 32 + (lane >> 4) * 8];
        oacc[df] = __builtin_amdgcn_mfma_f32_16x16x32_bf16(pf, vf, oacc[df], 0, 0, 0);
      }
    }
  }
#pragma unroll
  for (int df = 0; df < 4; ++df)
#pragma unroll
    for (int r = 0; r < 4; ++r) {
      int qr = q0 + wid * 16 + ((lane >> 4) << 2) + r;
      int d = df * 16 + (lane & 15);
      size_t grow = (size_t)b * 2048 + qr;
      float gate = bf2f(qgk[grow * 4608 + 2048 + h * 64 + d]);
      float g = 1.f / (1.f + __expf(-gate));
      float o = oacc[df][r] / lrow[r];
      attng[grow * 2048 + h * 64 + d] = f2bf(o * g);
    }
}

extern "C" void kernel_launch(void* const* d_in, const int* in_sizes, int n_in,
                              void* d_out, int out_size, void* d_ws, size_t ws_size,
                              hipStream_t stream) {
  const float* hidden = (const float*)d_in[0];
  const float* cosT = (const float*)d_in[1];
  const float* sinT = (const float*)d_in[2];
  const float* wq = (const float*)d_in[4];
  const float* wk = (const float*)d_in[5];
  const float* wo = (const float*)d_in[7];
  char* ws = (char*)d_ws;
  unsigned short* hb16  = (unsigned short*)(ws + 0);          // 4096x2048 bf16
  unsigned short* wcatT = (unsigned short*)(ws + 16777216);   // 4608x2048 bf16 (wq^T rows 0..4095, wk^T rows 4096..4607)
  unsigned short* woT   = (unsigned short*)(ws + 35651584);   // 2048x2048 bf16
  unsigned short* qgk   = (unsigned short*)(ws + 44040192);   // 4096x4608 bf16 (q | gate | k)
  unsigned short* qrope = (unsigned short*)(ws + 81788928);   // [2][32][2048][64] bf16
  unsigned short* krope = (unsigned short*)(ws + 98566144);   // [2][8][2048][64] bf16
  unsigned short* kTb   = (unsigned short*)(ws + 102760448);  // [2][8][64][2048] bf16
  unsigned short* attng = (unsigned short*)(ws + 106954752);  // 4096x2048 bf16

  conv_bf16<<<dim3(2048), dim3(256), 0, stream>>>(hidden, hb16, 2097152);
  tconv<<<dim3(128, 64), dim3(32, 8), 0, stream>>>(wq, wcatT, 4096, 0, 2048);
  tconv<<<dim3(16, 64), dim3(32, 8), 0, stream>>>(wk, wcatT, 512, 4096, 2048);
  tconv<<<dim3(64, 64), dim3(32, 8), 0, stream>>>(wo, woT, 2048, 0, 2048);
  gemm_bt<unsigned short><<<dim3(36, 32), dim3(256), 0, stream>>>(hb16, wcatT, qgk, 4096, 4608, 2048);
  rope_qk<<<dim3(1024, 40), dim3(256), 0, stream>>>(qgk, cosT, sinT, qrope, krope);
  ktrans<<<dim3(32, 16), dim3(256), 0, stream>>>(krope, kTb);
  attn_fused<<<dim3(32, 64), dim3(256), 0, stream>>>(qrope, krope, kTb, qgk, attng);
  gemm_bt<float><<<dim3(16, 32), dim3(256), 0, stream>>>(attng, woT, (float*)d_out, 4096, 2048, 2048);
}

// Round 2
// 428.253 us; speedup vs baseline: 1.1280x; 1.1280x over previous
//
#include <hip/hip_runtime.h>

typedef float f32x4 __attribute__((ext_vector_type(4)));
typedef short bf16x8 __attribute__((ext_vector_type(8)));

__device__ __forceinline__ float bf2f(unsigned short h) {
  return __uint_as_float(((unsigned int)h) << 16);
}
__device__ __forceinline__ unsigned short f2bf(float f) {
  unsigned int u = __float_as_uint(f);
  unsigned int r = u + 0x7fffu + ((u >> 16) & 1u);
  return (unsigned short)(r >> 16);
}

__device__ __forceinline__ void gload_lds16(const void* g, void* l) {
  __builtin_amdgcn_global_load_lds((const __attribute__((address_space(1))) void*)g,
                                   (__attribute__((address_space(3))) void*)l, 16, 0, 0);
}

// ---------------- fp32 -> bf16 elementwise convert (vectorized) ----------------
__global__ void conv_bf16(const float* __restrict__ src, unsigned short* __restrict__ dst, int n4) {
  for (int i = blockIdx.x * blockDim.x + threadIdx.x; i < n4; i += gridDim.x * blockDim.x) {
    float4 v = ((const float4*)src)[i];
    ushort4 o;
    o.x = f2bf(v.x); o.y = f2bf(v.y); o.z = f2bf(v.z); o.w = f2bf(v.w);
    ((ushort4*)dst)[i] = o;
  }
}

// ------------- fp32 [R][C] -> bf16 dst[C + dstRowOff][R] transpose-convert -------------
__global__ void tconv(const float* __restrict__ src, unsigned short* __restrict__ dst,
                      int C, int dstRowOff, int dstLD) {
  __shared__ float tile[32][33];
  int c0 = blockIdx.x * 32, r0 = blockIdx.y * 32;
  int tx = threadIdx.x, ty = threadIdx.y;
#pragma unroll
  for (int i = 0; i < 4; ++i)
    tile[ty + i * 8][tx] = src[(size_t)(r0 + ty + i * 8) * C + c0 + tx];
  __syncthreads();
#pragma unroll
  for (int i = 0; i < 4; ++i)
    dst[(size_t)(dstRowOff + c0 + ty + i * 8) * dstLD + r0 + tx] = f2bf(tile[tx][ty + i * 8]);
}

// ---------------- GEMM: C[M][N] = A[M][K] * BT[N][K]^T, bf16 in, OutT out ----------------
template <typename OutT>
__global__ __launch_bounds__(256) void gemm_bt(const unsigned short* __restrict__ A,
                                               const unsigned short* __restrict__ BT,
                                               OutT* __restrict__ C, int M, int N, int K) {
  __shared__ unsigned short As[128 * 32];
  __shared__ unsigned short Bs[128 * 32];
  const int tid = threadIdx.x;
  const int lane = tid & 63;
  const int wid = tid >> 6;
  const int wr = wid >> 1, wc = wid & 1;
  const int bm = blockIdx.y, bn = blockIdx.x;
  const unsigned short* Ab = A + (size_t)bm * 128 * K;
  const unsigned short* Bb = BT + (size_t)bn * 128 * K;
  f32x4 acc[4][4] = {};
  const int f0 = tid * 8;
  const int row0 = f0 >> 5, col0 = f0 & 31;
  const int f1 = 2048 + tid * 8;
  const int row1 = f1 >> 5, col1 = f1 & 31;
  for (int k0 = 0; k0 < K; k0 += 32) {
    gload_lds16(Ab + (size_t)row0 * K + k0 + col0, &As[wid * 512]);
    gload_lds16(Ab + (size_t)row1 * K + k0 + col1, &As[2048 + wid * 512]);
    gload_lds16(Bb + (size_t)row0 * K + k0 + col0, &Bs[wid * 512]);
    gload_lds16(Bb + (size_t)row1 * K + k0 + col1, &Bs[2048 + wid * 512]);
    __syncthreads();
    bf16x8 af[4], bfr[4];
#pragma unroll
    for (int i = 0; i < 4; ++i) {
      af[i] = *(const bf16x8*)&As[(wr * 64 + i * 16 + (lane & 15)) * 32 + (lane >> 4) * 8];
      bfr[i] = *(const bf16x8*)&Bs[(wc * 64 + i * 16 + (lane & 15)) * 32 + (lane >> 4) * 8];
    }
#pragma unroll
    for (int i = 0; i < 4; ++i)
#pragma unroll
      for (int j = 0; j < 4; ++j)
        acc[i][j] = __builtin_amdgcn_mfma_f32_16x16x32_bf16(af[i], bfr[j], acc[i][j], 0, 0, 0);
    __syncthreads();
  }
  const int rbase = bm * 128 + wr * 64 + ((lane >> 4) << 2);
  const int cbase = bn * 128 + wc * 64 + (lane & 15);
#pragma unroll
  for (int i = 0; i < 4; ++i)
#pragma unroll
    for (int j = 0; j < 4; ++j)
#pragma unroll
      for (int r = 0; r < 4; ++r) {
        int row = rbase + i * 16 + r;
        int col = cbase + j * 16;
        if constexpr (sizeof(OutT) == 2)
          C[(size_t)row * N + col] = f2bf(acc[i][j][r]);
        else
          C[(size_t)row * N + col] = acc[i][j][r];
      }
}

// ---------------- RoPE: qgk cols -> head-major roped q/k ----------------
__global__ void rope_qk(const unsigned short* __restrict__ qgk, const float* __restrict__ cosT,
                        const float* __restrict__ sinT, unsigned short* __restrict__ qrope,
                        unsigned short* __restrict__ krope) {
  int head = blockIdx.y;       // 0..31 q heads, 32..39 kv heads
  int tid = threadIdx.x;       // 256 = 4 rows x 64 dims
  int d = tid & 63;
  int row = blockIdx.x * 4 + (tid >> 6);  // 0..4095  (= b*2048 + s)
  int b = row >> 11, s = row & 2047;
  int base = (head < 32) ? head * 64 : 4096 + (head - 32) * 64;
  size_t off = (size_t)row * 4608 + base;
  float x = bf2f(qgk[off + d]);
  float xp = bf2f(qgk[off + (d ^ 32)]);
  float c = cosT[s * 64 + d], sn = sinT[s * 64 + d];
  float v = x * c + ((d < 32) ? -xp : xp) * sn;
  if (head < 32)
    qrope[((size_t)(b * 32 + head) * 2048 + s) * 64 + d] = f2bf(v);
  else
    krope[((size_t)(b * 8 + (head - 32)) * 2048 + s) * 64 + d] = f2bf(v);
}

// ---------------- krope [bh][2048][64] -> kT [bh][64][2048] ----------------
__global__ void ktrans(const unsigned short* __restrict__ krope, unsigned short* __restrict__ kT) {
  __shared__ unsigned short tile[64][65];
  int bh = blockIdx.y;
  int s0 = blockIdx.x * 64;
  const unsigned short* src = krope + (size_t)bh * 2048 * 64;
  unsigned short* dst = kT + (size_t)bh * 64 * 2048;
  int tx = threadIdx.x & 63, ty = threadIdx.x >> 6;
#pragma unroll
  for (int i = 0; i < 16; ++i)
    tile[ty + i * 4][tx] = src[(size_t)(s0 + ty + i * 4) * 64 + tx];
  __syncthreads();
#pragma unroll
  for (int i = 0; i < 16; ++i)
    dst[(size_t)(ty + i * 4) * 2048 + s0 + tx] = tile[tx][ty + i * 4];
}

// ---------------- fused causal flash attention (V == roped K), gated epilogue ----------------
// 128 q-rows/block, 4 waves x 32 rows; XOR-swizzled LDS; double-buffered K/KT staging.
__global__ __launch_bounds__(256) void attn_fused(const unsigned short* __restrict__ qrope,
                                                  const unsigned short* __restrict__ krope,
                                                  const unsigned short* __restrict__ kT,
                                                  const unsigned short* __restrict__ qgk,
                                                  unsigned short* __restrict__ attng) {
  __shared__ unsigned short Ks[2][64 * 64];
  __shared__ unsigned short KTs[2][64 * 64];
  __shared__ unsigned short Ps[128 * 64];  // Q staging, then P tiles
  const int qblk = 15 - blockIdx.x;       // long blocks dispatched first
  const int bh = blockIdx.y;              // 0..63
  const int b = bh >> 5, h = bh & 31, kh = h >> 2;
  const int q0 = qblk * 128;
  const int tid = threadIdx.x, lane = tid & 63, wid = tid >> 6;
  const unsigned short* Qbase = qrope + ((size_t)(b * 32 + h) * 2048 + q0) * 64;
  const unsigned short* Kbase = krope + (size_t)(b * 8 + kh) * 2048 * 64;
  const unsigned short* KTbase = kT + (size_t)(b * 8 + kh) * 64 * 2048;

  // ---- stage Q (16KB) into Ps, swizzled-source / linear-LDS ----
#pragma unroll
  for (int j = 0; j < 4; ++j) {
    int F = ((j * 4 + wid) << 10) + (lane << 4);  // byte offset in tile
    int R = F >> 7;
    int cs = ((F >> 4) & 7) ^ (R & 7);
    gload_lds16(Qbase + (size_t)R * 64 + cs * 8, &Ps[(j * 4 + wid) << 9]);
  }
  // ---- stage K/KT tile 0 into buffer 0 ----
  {
#pragma unroll
    for (int j = 0; j < 2; ++j) {
      int F = ((j * 4 + wid) << 10) + (lane << 4);
      int R = F >> 7;
      int cs = ((F >> 4) & 7) ^ (R & 7);
      gload_lds16(Kbase + (size_t)R * 64 + cs * 8, &Ks[0][(j * 4 + wid) << 9]);
      gload_lds16(KTbase + (size_t)R * 2048 + cs * 8, &KTs[0][(j * 4 + wid) << 9]);
    }
  }
  __syncthreads();

  // ---- Q fragments (swizzled read) ----
  bf16x8 qf[2][2];
#pragma unroll
  for (int i = 0; i < 2; ++i)
#pragma unroll
    for (int ks = 0; ks < 2; ++ks) {
      int row = wid * 32 + i * 16 + (lane & 15);
      int ch = (ks * 4 + (lane >> 4)) ^ (row & 7);
      qf[i][ks] = *(const bf16x8*)&Ps[row * 64 + ch * 8];
    }
  __syncthreads();  // all waves have Q; Ps reusable

  f32x4 oacc[2][4] = {};
  float mrow[2][4], lrow[2][4];
#pragma unroll
  for (int i = 0; i < 2; ++i)
#pragma unroll
    for (int r = 0; r < 4; ++r) { mrow[i][r] = -1e30f; lrow[i][r] = 0.f; }

  const int nt = 2 * qblk + 2;
  for (int t = 0; t < nt; ++t) {
    const int cur = t & 1;
    if (t + 1 < nt) {
      const int nb = cur ^ 1;
#pragma unroll
      for (int j = 0; j < 2; ++j) {
        int F = ((j * 4 + wid) << 10) + (lane << 4);
        int R = F >> 7;
        int cs = ((F >> 4) & 7) ^ (R & 7);
        gload_lds16(Kbase + (size_t)((t + 1) * 64 + R) * 64 + cs * 8, &Ks[nb][(j * 4 + wid) << 9]);
        gload_lds16(KTbase + (size_t)R * 2048 + (t + 1) * 64 + cs * 8, &KTs[nb][(j * 4 + wid) << 9]);
      }
    }
    // ---- QK^T ----
    f32x4 sc[2][4] = {};
#pragma unroll
    for (int ks = 0; ks < 2; ++ks) {
      bf16x8 kf[4];
#pragma unroll
      for (int nf = 0; nf < 4; ++nf) {
        int row = nf * 16 + (lane & 15);
        int ch = (ks * 4 + (lane >> 4)) ^ (row & 7);
        kf[nf] = *(const bf16x8*)&Ks[cur][row * 64 + ch * 8];
      }
#pragma unroll
      for (int i = 0; i < 2; ++i)
#pragma unroll
        for (int nf = 0; nf < 4; ++nf)
          sc[i][nf] = __builtin_amdgcn_mfma_f32_16x16x32_bf16(qf[i][ks], kf[nf], sc[i][nf], 0, 0, 0);
    }
    if (t >= 2 * qblk) {
#pragma unroll
      for (int i = 0; i < 2; ++i)
#pragma unroll
        for (int nf = 0; nf < 4; ++nf)
#pragma unroll
          for (int r = 0; r < 4; ++r) {
            int kabs = t * 64 + nf * 16 + (lane & 15);
            int qabs = q0 + wid * 32 + i * 16 + ((lane >> 4) << 2) + r;
            if (kabs > qabs) sc[i][nf][r] += -1e9f;
          }
    }
    // ---- online softmax ----
    float scale[2][4];
#pragma unroll
    for (int i = 0; i < 2; ++i)
#pragma unroll
      for (int r = 0; r < 4; ++r) {
        float pm = fmaxf(fmaxf(sc[i][0][r], sc[i][1][r]), fmaxf(sc[i][2][r], sc[i][3][r]));
#pragma unroll
        for (int msk = 1; msk < 16; msk <<= 1) pm = fmaxf(pm, __shfl_xor(pm, msk, 64));
        float mnew = fmaxf(mrow[i][r], pm);
        scale[i][r] = __expf(mrow[i][r] - mnew);
        mrow[i][r] = mnew;
      }
    float rs[2][4] = {};
#pragma unroll
    for (int i = 0; i < 2; ++i)
#pragma unroll
      for (int nf = 0; nf < 4; ++nf)
#pragma unroll
        for (int r = 0; r < 4; ++r) {
          float p = __expf(sc[i][nf][r] - mrow[i][r]);
          sc[i][nf][r] = p;
          rs[i][r] += p;
        }
#pragma unroll
    for (int i = 0; i < 2; ++i)
#pragma unroll
      for (int r = 0; r < 4; ++r) {
#pragma unroll
        for (int msk = 1; msk < 16; msk <<= 1) rs[i][r] += __shfl_xor(rs[i][r], msk, 64);
        lrow[i][r] = lrow[i][r] * scale[i][r] + rs[i][r];
#pragma unroll
        for (int df = 0; df < 4; ++df) oacc[i][df][r] *= scale[i][r];
      }
    // ---- write P (swizzled) ----
#pragma unroll
    for (int i = 0; i < 2; ++i)
#pragma unroll
      for (int nf = 0; nf < 4; ++nf)
#pragma unroll
        for (int r = 0; r < 4; ++r) {
          int qr = wid * 32 + i * 16 + ((lane >> 4) << 2) + r;
          int colb = nf * 32 + (lane & 15) * 2;
          int ch = (colb >> 4) ^ (qr & 7);
          Ps[qr * 64 + ch * 8 + ((colb >> 1) & 7)] = f2bf(sc[i][nf][r]);
        }
    __syncthreads();
    // ---- PV (V == K, via KT) ----
#pragma unroll
    for (int ks = 0; ks < 2; ++ks) {
      bf16x8 pf[2], vf[4];
#pragma unroll
      for (int i = 0; i < 2; ++i) {
        int row = wid * 32 + i * 16 + (lane & 15);
        int ch = (ks * 4 + (lane >> 4)) ^ (row & 7);
        pf[i] = *(const bf16x8*)&Ps[row * 64 + ch * 8];
      }
#pragma unroll
      for (int df = 0; df < 4; ++df) {
        int row = df * 16 + (lane & 15);
        int ch = (ks * 4 + (lane >> 4)) ^ (row & 7);
        vf[df] = *(const bf16x8*)&KTs[cur][row * 64 + ch * 8];
      }
#pragma unroll
      for (int i = 0; i < 2; ++i)
#pragma unroll
        for (int df = 0; df < 4; ++df)
          oacc[i][df] = __builtin_amdgcn_mfma_f32_16x16x32_bf16(pf[i], vf[df], oacc[i][df], 0, 0, 0);
    }
    __syncthreads();
  }
  // ---- gated epilogue ----
#pragma unroll
  for (int i = 0; i < 2; ++i)
#pragma unroll
    for (int df = 0; df < 4; ++df)
#pragma unroll
      for (int r = 0; r < 4; ++r) {
        int qr = q0 + wid * 32 + i * 16 + ((lane >> 4) << 2) + r;
        int d = df * 16 + (lane & 15);
        size_t grow = (size_t)b * 2048 + qr;
        float gate = bf2f(qgk[grow * 4608 + 2048 + h * 64 + d]);
        float g = 1.f / (1.f + __expf(-gate));
        float o = oacc[i][df][r] / lrow[i][r];
        attng[grow * 2048 + h * 64 + d] = f2bf(o * g);
      }
}

extern "C" void kernel_launch(void* const* d_in, const int* in_sizes, int n_in,
                              void* d_out, int out_size, void* d_ws, size_t ws_size,
                              hipStream_t stream) {
  const float* hidden = (const float*)d_in[0];
  const float* cosT = (const float*)d_in[1];
  const float* sinT = (const float*)d_in[2];
  const float* wq = (const float*)d_in[4];
  const float* wk = (const float*)d_in[5];
  const float* wo = (const float*)d_in[7];
  char* ws = (char*)d_ws;
  unsigned short* hb16  = (unsigned short*)(ws + 0);          // 4096x2048 bf16
  unsigned short* wcatT = (unsigned short*)(ws + 16777216);   // 4608x2048 bf16 (wq^T rows 0..4095, wk^T rows 4096..4607)
  unsigned short* woT   = (unsigned short*)(ws + 35651584);   // 2048x2048 bf16
  unsigned short* qgk   = (unsigned short*)(ws + 44040192);   // 4096x4608 bf16 (q | gate | k)
  unsigned short* qrope = (unsigned short*)(ws + 81788928);   // [2][32][2048][64] bf16
  unsigned short* krope = (unsigned short*)(ws + 98566144);   // [2][8][2048][64] bf16
  unsigned short* kTb   = (unsigned short*)(ws + 102760448);  // [2][8][64][2048] bf16
  unsigned short* attng = (unsigned short*)(ws + 106954752);  // 4096x2048 bf16

  conv_bf16<<<dim3(2048), dim3(256), 0, stream>>>(hidden, hb16, 2097152);
  tconv<<<dim3(128, 64), dim3(32, 8), 0, stream>>>(wq, wcatT, 4096, 0, 2048);
  tconv<<<dim3(16, 64), dim3(32, 8), 0, stream>>>(wk, wcatT, 512, 4096, 2048);
  tconv<<<dim3(64, 64), dim3(32, 8), 0, stream>>>(wo, woT, 2048, 0, 2048);
  gemm_bt<unsigned short><<<dim3(36, 32), dim3(256), 0, stream>>>(hb16, wcatT, qgk, 4096, 4608, 2048);
  rope_qk<<<dim3(1024, 40), dim3(256), 0, stream>>>(qgk, cosT, sinT, qrope, krope);
  ktrans<<<dim3(32, 16), dim3(256), 0, stream>>>(krope, kTb);
  attn_fused<<<dim3(16, 64), dim3(256), 0, stream>>>(qrope, krope, kTb, qgk, attng);
  gemm_bt<float><<<dim3(16, 32), dim3(256), 0, stream>>>(attng, woT, (float*)d_out, 4096, 2048, 2048);
}

// Round 3
// 351.021 us; speedup vs baseline: 1.3762x; 1.2200x over previous
//
#include <hip/hip_runtime.h>

typedef float f32x4 __attribute__((ext_vector_type(4)));
typedef short bf16x8 __attribute__((ext_vector_type(8)));

__device__ __forceinline__ float bf2f(unsigned short h) {
  return __uint_as_float(((unsigned int)h) << 16);
}
__device__ __forceinline__ unsigned short f2bf(float f) {
  unsigned int u = __float_as_uint(f);
  unsigned int r = u + 0x7fffu + ((u >> 16) & 1u);
  return (unsigned short)(r >> 16);
}

__device__ __forceinline__ void gload_lds16(const void* g, void* l) {
  __builtin_amdgcn_global_load_lds((const __attribute__((address_space(1))) void*)g,
                                   (__attribute__((address_space(3))) void*)l, 16, 0, 0);
}

// ---------------- fp32 -> bf16 elementwise convert (vectorized) ----------------
__global__ void conv_bf16(const float* __restrict__ src, unsigned short* __restrict__ dst, int n4) {
  for (int i = blockIdx.x * blockDim.x + threadIdx.x; i < n4; i += gridDim.x * blockDim.x) {
    float4 v = ((const float4*)src)[i];
    ushort4 o;
    o.x = f2bf(v.x); o.y = f2bf(v.y); o.z = f2bf(v.z); o.w = f2bf(v.w);
    ((ushort4*)dst)[i] = o;
  }
}

// ------------- fp32 [R][C] -> bf16 dst[C + dstRowOff][R] transpose-convert -------------
__global__ void tconv(const float* __restrict__ src, unsigned short* __restrict__ dst,
                      int C, int dstRowOff, int dstLD) {
  __shared__ float tile[32][33];
  int c0 = blockIdx.x * 32, r0 = blockIdx.y * 32;
  int tx = threadIdx.x, ty = threadIdx.y;
#pragma unroll
  for (int i = 0; i < 4; ++i)
    tile[ty + i * 8][tx] = src[(size_t)(r0 + ty + i * 8) * C + c0 + tx];
  __syncthreads();
#pragma unroll
  for (int i = 0; i < 4; ++i)
    dst[(size_t)(dstRowOff + c0 + ty + i * 8) * dstLD + r0 + tx] = f2bf(tile[tx][ty + i * 8]);
}

// ---------------- GEMM: C[M][N] = A[M][K] * BT[N][K]^T, bf16 in, OutT out ----------------
template <typename OutT>
__global__ __launch_bounds__(256) void gemm_bt(const unsigned short* __restrict__ A,
                                               const unsigned short* __restrict__ BT,
                                               OutT* __restrict__ C, int M, int N, int K) {
  __shared__ unsigned short As[128 * 32];
  __shared__ unsigned short Bs[128 * 32];
  const int tid = threadIdx.x;
  const int lane = tid & 63;
  const int wid = tid >> 6;
  const int wr = wid >> 1, wc = wid & 1;
  const int bm = blockIdx.y, bn = blockIdx.x;
  const unsigned short* Ab = A + (size_t)bm * 128 * K;
  const unsigned short* Bb = BT + (size_t)bn * 128 * K;
  f32x4 acc[4][4] = {};
  const int f0 = tid * 8;
  const int row0 = f0 >> 5, col0 = f0 & 31;
  const int f1 = 2048 + tid * 8;
  const int row1 = f1 >> 5, col1 = f1 & 31;
  for (int k0 = 0; k0 < K; k0 += 32) {
    gload_lds16(Ab + (size_t)row0 * K + k0 + col0, &As[wid * 512]);
    gload_lds16(Ab + (size_t)row1 * K + k0 + col1, &As[2048 + wid * 512]);
    gload_lds16(Bb + (size_t)row0 * K + k0 + col0, &Bs[wid * 512]);
    gload_lds16(Bb + (size_t)row1 * K + k0 + col1, &Bs[2048 + wid * 512]);
    __syncthreads();
    bf16x8 af[4], bfr[4];
#pragma unroll
    for (int i = 0; i < 4; ++i) {
      af[i] = *(const bf16x8*)&As[(wr * 64 + i * 16 + (lane & 15)) * 32 + (lane >> 4) * 8];
      bfr[i] = *(const bf16x8*)&Bs[(wc * 64 + i * 16 + (lane & 15)) * 32 + (lane >> 4) * 8];
    }
#pragma unroll
    for (int i = 0; i < 4; ++i)
#pragma unroll
      for (int j = 0; j < 4; ++j)
        acc[i][j] = __builtin_amdgcn_mfma_f32_16x16x32_bf16(af[i], bfr[j], acc[i][j], 0, 0, 0);
    __syncthreads();
  }
  const int rbase = bm * 128 + wr * 64 + ((lane >> 4) << 2);
  const int cbase = bn * 128 + wc * 64 + (lane & 15);
#pragma unroll
  for (int i = 0; i < 4; ++i)
#pragma unroll
    for (int j = 0; j < 4; ++j)
#pragma unroll
      for (int r = 0; r < 4; ++r) {
        int row = rbase + i * 16 + r;
        int col = cbase + j * 16;
        if constexpr (sizeof(OutT) == 2)
          C[(size_t)row * N + col] = f2bf(acc[i][j][r]);
        else
          C[(size_t)row * N + col] = acc[i][j][r];
      }
}

// ---------------- RoPE: qgk cols -> head-major roped q/k ----------------
__global__ void rope_qk(const unsigned short* __restrict__ qgk, const float* __restrict__ cosT,
                        const float* __restrict__ sinT, unsigned short* __restrict__ qrope,
                        unsigned short* __restrict__ krope) {
  int head = blockIdx.y;       // 0..31 q heads, 32..39 kv heads
  int tid = threadIdx.x;       // 256 = 4 rows x 64 dims
  int d = tid & 63;
  int row = blockIdx.x * 4 + (tid >> 6);  // 0..4095  (= b*2048 + s)
  int b = row >> 11, s = row & 2047;
  int base = (head < 32) ? head * 64 : 4096 + (head - 32) * 64;
  size_t off = (size_t)row * 4608 + base;
  float x = bf2f(qgk[off + d]);
  float xp = bf2f(qgk[off + (d ^ 32)]);
  float c = cosT[s * 64 + d], sn = sinT[s * 64 + d];
  float v = x * c + ((d < 32) ? -xp : xp) * sn;
  if (head < 32)
    qrope[((size_t)(b * 32 + head) * 2048 + s) * 64 + d] = f2bf(v);
  else
    krope[((size_t)(b * 8 + (head - 32)) * 2048 + s) * 64 + d] = f2bf(v);
}

// ---------------- krope [bh][2048][64] -> kT [bh][64][2048] ----------------
__global__ void ktrans(const unsigned short* __restrict__ krope, unsigned short* __restrict__ kT) {
  __shared__ unsigned short tile[64][65];
  int bh = blockIdx.y;
  int s0 = blockIdx.x * 64;
  const unsigned short* src = krope + (size_t)bh * 2048 * 64;
  unsigned short* dst = kT + (size_t)bh * 64 * 2048;
  int tx = threadIdx.x & 63, ty = threadIdx.x >> 6;
#pragma unroll
  for (int i = 0; i < 16; ++i)
    tile[ty + i * 4][tx] = src[(size_t)(s0 + ty + i * 4) * 64 + tx];
  __syncthreads();
#pragma unroll
  for (int i = 0; i < 16; ++i)
    dst[(size_t)(ty + i * 4) * 2048 + s0 + tx] = tile[tx][ty + i * 4];
}

// ---------------- fused causal flash attention (V == roped K), gated epilogue ----------------
// 128 q-rows/block, 4 waves x 32 rows; XOR-swizzled LDS; double-buffered K/KT staging.
// Swapped QK^T (S^T = mfma(K,Q)) -> in-register softmax (2 shfl per reduce);
// O^T = mfma(V^T, P) so softmax state and O columns share q = lane&15.
__global__ __launch_bounds__(256) void attn_fused(const unsigned short* __restrict__ qrope,
                                                  const unsigned short* __restrict__ krope,
                                                  const unsigned short* __restrict__ kT,
                                                  const unsigned short* __restrict__ qgk,
                                                  unsigned short* __restrict__ attng) {
  __shared__ unsigned short Ks[2][64 * 64];
  __shared__ unsigned short KTs[2][64 * 64];
  __shared__ unsigned short Ps[128 * 64];  // Q staging, then P tiles
  const int qblk = 15 - blockIdx.x;       // long blocks dispatched first
  const int bh = blockIdx.y;              // 0..63
  const int b = bh >> 5, h = bh & 31, kh = h >> 2;
  const int q0 = qblk * 128;
  const int tid = threadIdx.x, lane = tid & 63, wid = tid >> 6;
  const int g = lane >> 4, l15 = lane & 15;
  const unsigned short* Qbase = qrope + ((size_t)(b * 32 + h) * 2048 + q0) * 64;
  const unsigned short* Kbase = krope + (size_t)(b * 8 + kh) * 2048 * 64;
  const unsigned short* KTbase = kT + (size_t)(b * 8 + kh) * 64 * 2048;

  // ---- stage Q (16KB) into Ps, swizzled-source / linear-LDS ----
#pragma unroll
  for (int j = 0; j < 4; ++j) {
    int F = ((j * 4 + wid) << 10) + (lane << 4);  // byte offset in tile
    int R = F >> 7;
    int cs = ((F >> 4) & 7) ^ (R & 7);
    gload_lds16(Qbase + (size_t)R * 64 + cs * 8, &Ps[(j * 4 + wid) << 9]);
  }
  // ---- stage K/KT tile 0 into buffer 0 ----
  {
#pragma unroll
    for (int j = 0; j < 2; ++j) {
      int F = ((j * 4 + wid) << 10) + (lane << 4);
      int R = F >> 7;
      int cs = ((F >> 4) & 7) ^ (R & 7);
      gload_lds16(Kbase + (size_t)R * 64 + cs * 8, &Ks[0][(j * 4 + wid) << 9]);
      gload_lds16(KTbase + (size_t)R * 2048 + cs * 8, &KTs[0][(j * 4 + wid) << 9]);
    }
  }
  __syncthreads();

  // ---- Q fragments (swizzled read) ----
  bf16x8 qf[2][2];
#pragma unroll
  for (int i = 0; i < 2; ++i)
#pragma unroll
    for (int ks = 0; ks < 2; ++ks) {
      int row = wid * 32 + i * 16 + l15;
      int ch = (ks * 4 + g) ^ (row & 7);
      qf[i][ks] = *(const bf16x8*)&Ps[row * 64 + ch * 8];
    }
  __syncthreads();  // all waves have Q; Ps reusable

  f32x4 oaccT[2][4] = {};
  float mrow[2] = {-1e30f, -1e30f}, lrow[2] = {0.f, 0.f};

  const int nt = 2 * qblk + 2;
  for (int t = 0; t < nt; ++t) {
    const int cur = t & 1;
    if (t + 1 < nt) {
      const int nb = cur ^ 1;
#pragma unroll
      for (int j = 0; j < 2; ++j) {
        int F = ((j * 4 + wid) << 10) + (lane << 4);
        int R = F >> 7;
        int cs = ((F >> 4) & 7) ^ (R & 7);
        gload_lds16(Kbase + (size_t)((t + 1) * 64 + R) * 64 + cs * 8, &Ks[nb][(j * 4 + wid) << 9]);
        gload_lds16(KTbase + (size_t)R * 2048 + (t + 1) * 64 + cs * 8, &KTs[nb][(j * 4 + wid) << 9]);
      }
    }
    // ---- S^T = K * Q^T  (rows = keys, cols = q) ----
    f32x4 st[2][4] = {};
#pragma unroll
    for (int ks = 0; ks < 2; ++ks) {
      bf16x8 kf[4];
#pragma unroll
      for (int nf = 0; nf < 4; ++nf) {
        int row = nf * 16 + l15;
        int ch = (ks * 4 + g) ^ (row & 7);
        kf[nf] = *(const bf16x8*)&Ks[cur][row * 64 + ch * 8];
      }
#pragma unroll
      for (int i = 0; i < 2; ++i)
#pragma unroll
        for (int nf = 0; nf < 4; ++nf)
          st[i][nf] = __builtin_amdgcn_mfma_f32_16x16x32_bf16(kf[nf], qf[i][ks], st[i][nf], 0, 0, 0);
    }
    if (t >= 2 * qblk) {
#pragma unroll
      for (int i = 0; i < 2; ++i) {
        int qabs = q0 + wid * 32 + i * 16 + l15;
#pragma unroll
        for (int nf = 0; nf < 4; ++nf)
#pragma unroll
          for (int r = 0; r < 4; ++r) {
            int kabs = t * 64 + nf * 16 + 4 * g + r;
            if (kabs > qabs) st[i][nf][r] += -1e9f;
          }
      }
    }
    // ---- online softmax (per-thread: q = lane&15 within frag i) ----
#pragma unroll
    for (int i = 0; i < 2; ++i) {
      float pm = st[i][0][0];
#pragma unroll
      for (int nf = 0; nf < 4; ++nf)
#pragma unroll
        for (int r = 0; r < 4; ++r) pm = fmaxf(pm, st[i][nf][r]);
      pm = fmaxf(pm, __shfl_xor(pm, 16, 64));
      pm = fmaxf(pm, __shfl_xor(pm, 32, 64));
      float mnew = fmaxf(mrow[i], pm);
      float scale = __expf(mrow[i] - mnew);
      mrow[i] = mnew;
      float rs = 0.f;
#pragma unroll
      for (int nf = 0; nf < 4; ++nf)
#pragma unroll
        for (int r = 0; r < 4; ++r) {
          float p = __expf(st[i][nf][r] - mnew);
          st[i][nf][r] = p;
          rs += p;
        }
      rs += __shfl_xor(rs, 16, 64);
      rs += __shfl_xor(rs, 32, 64);
      lrow[i] = lrow[i] * scale + rs;
#pragma unroll
      for (int df = 0; df < 4; ++df)
#pragma unroll
        for (int r = 0; r < 4; ++r) oaccT[i][df][r] *= scale;
    }
    // ---- write P rows (each lane: 4 consecutive keys per frag -> b64 writes) ----
#pragma unroll
    for (int i = 0; i < 2; ++i) {
      int q = wid * 32 + i * 16 + l15;
#pragma unroll
      for (int nf = 0; nf < 4; ++nf) {
        int k0 = nf * 16 + 4 * g;
        int ch = (k0 >> 3) ^ (q & 7);
        ushort4 pk;
        pk.x = f2bf(st[i][nf][0]);
        pk.y = f2bf(st[i][nf][1]);
        pk.z = f2bf(st[i][nf][2]);
        pk.w = f2bf(st[i][nf][3]);
        *(ushort4*)&Ps[q * 64 + ch * 8 + (k0 & 7)] = pk;
      }
    }
    __syncthreads();
    // ---- O^T += V^T * P^T  (rows = d, cols = q) ----
#pragma unroll
    for (int ks = 0; ks < 2; ++ks) {
      bf16x8 pf[2], vf[4];
#pragma unroll
      for (int i = 0; i < 2; ++i) {
        int row = wid * 32 + i * 16 + l15;
        int ch = (ks * 4 + g) ^ (row & 7);
        pf[i] = *(const bf16x8*)&Ps[row * 64 + ch * 8];
      }
#pragma unroll
      for (int df = 0; df < 4; ++df) {
        int row = df * 16 + l15;
        int ch = (ks * 4 + g) ^ (row & 7);
        vf[df] = *(const bf16x8*)&KTs[cur][row * 64 + ch * 8];
      }
#pragma unroll
      for (int i = 0; i < 2; ++i)
#pragma unroll
        for (int df = 0; df < 4; ++df)
          oaccT[i][df] = __builtin_amdgcn_mfma_f32_16x16x32_bf16(vf[df], pf[i], oaccT[i][df], 0, 0, 0);
    }
    __syncthreads();
  }
  // ---- gated epilogue (O^T: lane holds q = lane&15, d = df*16 + 4g + r) ----
#pragma unroll
  for (int i = 0; i < 2; ++i) {
    float rl = 1.f / lrow[i];
    int qabs = q0 + wid * 32 + i * 16 + l15;
    size_t grow = (size_t)b * 2048 + qabs;
#pragma unroll
    for (int df = 0; df < 4; ++df) {
      int d0 = df * 16 + 4 * g;
      ushort4 gt = *(const ushort4*)&qgk[grow * 4608 + 2048 + h * 64 + d0];
      ushort4 o;
      float gate, gg;
      gate = bf2f(gt.x); gg = 1.f / (1.f + __expf(-gate)); o.x = f2bf(oaccT[i][df][0] * rl * gg);
      gate = bf2f(gt.y); gg = 1.f / (1.f + __expf(-gate)); o.y = f2bf(oaccT[i][df][1] * rl * gg);
      gate = bf2f(gt.z); gg = 1.f / (1.f + __expf(-gate)); o.z = f2bf(oaccT[i][df][2] * rl * gg);
      gate = bf2f(gt.w); gg = 1.f / (1.f + __expf(-gate)); o.w = f2bf(oaccT[i][df][3] * rl * gg);
      *(ushort4*)&attng[grow * 2048 + h * 64 + d0] = o;
    }
  }
}

extern "C" void kernel_launch(void* const* d_in, const int* in_sizes, int n_in,
                              void* d_out, int out_size, void* d_ws, size_t ws_size,
                              hipStream_t stream) {
  const float* hidden = (const float*)d_in[0];
  const float* cosT = (const float*)d_in[1];
  const float* sinT = (const float*)d_in[2];
  const float* wq = (const float*)d_in[4];
  const float* wk = (const float*)d_in[5];
  const float* wo = (const float*)d_in[7];
  char* ws = (char*)d_ws;
  unsigned short* hb16  = (unsigned short*)(ws + 0);          // 4096x2048 bf16
  unsigned short* wcatT = (unsigned short*)(ws + 16777216);   // 4608x2048 bf16 (wq^T rows 0..4095, wk^T rows 4096..4607)
  unsigned short* woT   = (unsigned short*)(ws + 35651584);   // 2048x2048 bf16
  unsigned short* qgk   = (unsigned short*)(ws + 44040192);   // 4096x4608 bf16 (q | gate | k)
  unsigned short* qrope = (unsigned short*)(ws + 81788928);   // [2][32][2048][64] bf16
  unsigned short* krope = (unsigned short*)(ws + 98566144);   // [2][8][2048][64] bf16
  unsigned short* kTb   = (unsigned short*)(ws + 102760448);  // [2][8][64][2048] bf16
  unsigned short* attng = (unsigned short*)(ws + 106954752);  // 4096x2048 bf16

  conv_bf16<<<dim3(2048), dim3(256), 0, stream>>>(hidden, hb16, 2097152);
  tconv<<<dim3(128, 64), dim3(32, 8), 0, stream>>>(wq, wcatT, 4096, 0, 2048);
  tconv<<<dim3(16, 64), dim3(32, 8), 0, stream>>>(wk, wcatT, 512, 4096, 2048);
  tconv<<<dim3(64, 64), dim3(32, 8), 0, stream>>>(wo, woT, 2048, 0, 2048);
  gemm_bt<unsigned short><<<dim3(36, 32), dim3(256), 0, stream>>>(hb16, wcatT, qgk, 4096, 4608, 2048);
  rope_qk<<<dim3(1024, 40), dim3(256), 0, stream>>>(qgk, cosT, sinT, qrope, krope);
  ktrans<<<dim3(32, 16), dim3(256), 0, stream>>>(krope, kTb);
  attn_fused<<<dim3(16, 64), dim3(256), 0, stream>>>(qrope, krope, kTb, qgk, attng);
  gemm_bt<float><<<dim3(16, 32), dim3(256), 0, stream>>>(attng, woT, (float*)d_out, 4096, 2048, 2048);
}

// Round 5
// 249.188 us; speedup vs baseline: 1.9386x; 1.4087x over previous
//
#include <hip/hip_runtime.h>

typedef float f32x4 __attribute__((ext_vector_type(4)));
typedef short bf16x8 __attribute__((ext_vector_type(8)));

__device__ __forceinline__ float bf2f(unsigned short h) {
  return __uint_as_float(((unsigned int)h) << 16);
}
__device__ __forceinline__ unsigned short f2bf(float f) {
  unsigned int u = __float_as_uint(f);
  unsigned int r = u + 0x7fffu + ((u >> 16) & 1u);
  return (unsigned short)(r >> 16);
}
__device__ __forceinline__ float fast_exp2(float x) {
  return __builtin_amdgcn_exp2f(x);  // v_exp_f32: D = 2^S0
}

__device__ __forceinline__ void gload_lds16(const void* g, void* l) {
  __builtin_amdgcn_global_load_lds((const __attribute__((address_space(1))) void*)g,
                                   (__attribute__((address_space(3))) void*)l, 16, 0, 0);
}

// ---------------- fp32 -> bf16 elementwise convert (vectorized) ----------------
__global__ void conv_bf16(const float* __restrict__ src, unsigned short* __restrict__ dst, int n4) {
  for (int i = blockIdx.x * blockDim.x + threadIdx.x; i < n4; i += gridDim.x * blockDim.x) {
    float4 v = ((const float4*)src)[i];
    ushort4 o;
    o.x = f2bf(v.x); o.y = f2bf(v.y); o.z = f2bf(v.z); o.w = f2bf(v.w);
    ((ushort4*)dst)[i] = o;
  }
}

// ------------- fp32 [R][C] -> bf16 dst[C + dstRowOff][R] transpose-convert -------------
__global__ void tconv(const float* __restrict__ src, unsigned short* __restrict__ dst,
                      int C, int dstRowOff, int dstLD) {
  __shared__ float tile[32][33];
  int c0 = blockIdx.x * 32, r0 = blockIdx.y * 32;
  int tx = threadIdx.x, ty = threadIdx.y;
#pragma unroll
  for (int i = 0; i < 4; ++i)
    tile[ty + i * 8][tx] = src[(size_t)(r0 + ty + i * 8) * C + c0 + tx];
  __syncthreads();
#pragma unroll
  for (int i = 0; i < 4; ++i)
    dst[(size_t)(dstRowOff + c0 + ty + i * 8) * dstLD + r0 + tx] = f2bf(tile[tx][ty + i * 8]);
}

// ---------------- GEMM: C[M][N] = A[M][K] * BT[N][K]^T, bf16 in, OutT out ----------------
// m97 structure: 128x128 tile, BK=64, global_load_lds(16B), XOR-swizzled LDS.
template <typename OutT>
__global__ __launch_bounds__(256) void gemm_bt(const unsigned short* __restrict__ A,
                                               const unsigned short* __restrict__ BT,
                                               OutT* __restrict__ C, int M, int N, int K) {
  __shared__ unsigned short As[128 * 64];
  __shared__ unsigned short Bs[128 * 64];
  const int tid = threadIdx.x;
  const int lane = tid & 63;
  const int wid = tid >> 6;
  const int g = lane >> 4, l15 = lane & 15;
  const int wr = wid >> 1, wc = wid & 1;
  const int bm = blockIdx.y, bn = blockIdx.x;
  const unsigned short* Ab = A + (size_t)bm * 128 * K;
  const unsigned short* Bb = BT + (size_t)bn * 128 * K;
  f32x4 acc[4][4] = {};
  // staging geometry: chunk c = j*256 + tid (j=0..3); R = c>>3, cc = c&7, source col-chunk cs = cc^(R&7)
  int Rj[4], csj[4];
#pragma unroll
  for (int j = 0; j < 4; ++j) {
    int c = j * 256 + tid;
    Rj[j] = c >> 3;
    csj[j] = ((c & 7) ^ (Rj[j] & 7)) * 8;
  }
  for (int k0 = 0; k0 < K; k0 += 64) {
#pragma unroll
    for (int j = 0; j < 4; ++j) {
      gload_lds16(Ab + (size_t)Rj[j] * K + k0 + csj[j], &As[(j * 256 + (wid << 6)) * 8]);
      gload_lds16(Bb + (size_t)Rj[j] * K + k0 + csj[j], &Bs[(j * 256 + (wid << 6)) * 8]);
    }
    __syncthreads();
    bf16x8 af[4][2], bfr[4][2];
#pragma unroll
    for (int i = 0; i < 4; ++i)
#pragma unroll
      for (int kk = 0; kk < 2; ++kk) {
        int rowa = wr * 64 + i * 16 + l15;
        int cha = ((kk * 4 + g) ^ (rowa & 7)) * 8;
        af[i][kk] = *(const bf16x8*)&As[rowa * 64 + cha];
        int rowb = wc * 64 + i * 16 + l15;
        int chb = ((kk * 4 + g) ^ (rowb & 7)) * 8;
        bfr[i][kk] = *(const bf16x8*)&Bs[rowb * 64 + chb];
      }
    __builtin_amdgcn_s_setprio(1);
#pragma unroll
    for (int kk = 0; kk < 2; ++kk)
#pragma unroll
      for (int i = 0; i < 4; ++i)
#pragma unroll
        for (int j = 0; j < 4; ++j)
          acc[i][j] = __builtin_amdgcn_mfma_f32_16x16x32_bf16(af[i][kk], bfr[j][kk], acc[i][j], 0, 0, 0);
    __builtin_amdgcn_s_setprio(0);
    __syncthreads();
  }
  const int rbase = bm * 128 + wr * 64 + ((lane >> 4) << 2);
  const int cbase = bn * 128 + wc * 64 + l15;
#pragma unroll
  for (int i = 0; i < 4; ++i)
#pragma unroll
    for (int j = 0; j < 4; ++j)
#pragma unroll
      for (int r = 0; r < 4; ++r) {
        int row = rbase + i * 16 + r;
        int col = cbase + j * 16;
        if constexpr (sizeof(OutT) == 2)
          C[(size_t)row * N + col] = f2bf(acc[i][j][r]);
        else
          C[(size_t)row * N + col] = acc[i][j][r];
      }
}

// ---------------- RoPE: qgk cols -> head-major roped q/k (q scaled by log2e) ----------------
__global__ void rope_qk(const unsigned short* __restrict__ qgk, const float* __restrict__ cosT,
                        const float* __restrict__ sinT, unsigned short* __restrict__ qrope,
                        unsigned short* __restrict__ krope) {
  int head = blockIdx.y;       // 0..31 q heads, 32..39 kv heads
  int tid = threadIdx.x;       // 256 = 4 rows x 64 dims
  int d = tid & 63;
  int row = blockIdx.x * 4 + (tid >> 6);  // 0..4095  (= b*2048 + s)
  int b = row >> 11, s = row & 2047;
  int base = (head < 32) ? head * 64 : 4096 + (head - 32) * 64;
  size_t off = (size_t)row * 4608 + base;
  float x = bf2f(qgk[off + d]);
  float xp = bf2f(qgk[off + (d ^ 32)]);
  float c = cosT[s * 64 + d], sn = sinT[s * 64 + d];
  float v = x * c + ((d < 32) ? -xp : xp) * sn;
  if (head < 32)
    qrope[((size_t)(b * 32 + head) * 2048 + s) * 64 + d] = f2bf(v * 1.44269504089f);
  else
    krope[((size_t)(b * 8 + (head - 32)) * 2048 + s) * 64 + d] = f2bf(v);
}

// ---------------- krope [bh][2048][64] -> kT [bh][64][2048] ----------------
__global__ void ktrans(const unsigned short* __restrict__ krope, unsigned short* __restrict__ kT) {
  __shared__ unsigned short tile[64][65];
  int bh = blockIdx.y;
  int s0 = blockIdx.x * 64;
  const unsigned short* src = krope + (size_t)bh * 2048 * 64;
  unsigned short* dst = kT + (size_t)bh * 64 * 2048;
  int tx = threadIdx.x & 63, ty = threadIdx.x >> 6;
#pragma unroll
  for (int i = 0; i < 16; ++i)
    tile[ty + i * 4][tx] = src[(size_t)(s0 + ty + i * 4) * 64 + tx];
  __syncthreads();
#pragma unroll
  for (int i = 0; i < 16; ++i)
    dst[(size_t)(ty + i * 4) * 2048 + s0 + tx] = tile[tx][ty + i * 4];
}

// ---------------- fused causal flash attention (V == roped K), gated epilogue ----------------
// 128 q-rows/block, 4 waves x 32 rows; swapped QK^T, in-register softmax in exp2 domain,
// defer-max (THR=8), single barrier per tile (P is wave-private), setprio on MFMA.
__global__ __launch_bounds__(256) void attn_fused(const unsigned short* __restrict__ qrope,
                                                  const unsigned short* __restrict__ krope,
                                                  const unsigned short* __restrict__ kT,
                                                  const unsigned short* __restrict__ qgk,
                                                  unsigned short* __restrict__ attng) {
  __shared__ unsigned short Ks[2][64 * 64];
  __shared__ unsigned short KTs[2][64 * 64];
  __shared__ unsigned short Ps[128 * 64];  // Q staging, then P tiles (wave-private rows)
  const int qblk = 15 - blockIdx.y;       // long blocks dispatched first
  const int bh = blockIdx.x;              // 0..63
  const int b = bh >> 5, h = bh & 31, kh = h >> 2;
  const int q0 = qblk * 128;
  const int tid = threadIdx.x, lane = tid & 63, wid = tid >> 6;
  const int g = lane >> 4, l15 = lane & 15;
  const unsigned short* Qbase = qrope + ((size_t)(b * 32 + h) * 2048 + q0) * 64;
  const unsigned short* Kbase = krope + (size_t)(b * 8 + kh) * 2048 * 64;
  const unsigned short* KTbase = kT + (size_t)(b * 8 + kh) * 64 * 2048;

  // ---- stage Q (16KB) into Ps, swizzled-source / linear-LDS ----
#pragma unroll
  for (int j = 0; j < 4; ++j) {
    int F = ((j * 4 + wid) << 10) + (lane << 4);  // byte offset in tile
    int R = F >> 7;
    int cs = ((F >> 4) & 7) ^ (R & 7);
    gload_lds16(Qbase + (size_t)R * 64 + cs * 8, &Ps[(j * 4 + wid) << 9]);
  }
  // ---- stage K/KT tile 0 into buffer 0 ----
  {
#pragma unroll
    for (int j = 0; j < 2; ++j) {
      int F = ((j * 4 + wid) << 10) + (lane << 4);
      int R = F >> 7;
      int cs = ((F >> 4) & 7) ^ (R & 7);
      gload_lds16(Kbase + (size_t)R * 64 + cs * 8, &Ks[0][(j * 4 + wid) << 9]);
      gload_lds16(KTbase + (size_t)R * 2048 + cs * 8, &KTs[0][(j * 4 + wid) << 9]);
    }
  }
  __syncthreads();

  // ---- Q fragments (swizzled read) ----
  bf16x8 qf[2][2];
#pragma unroll
  for (int i = 0; i < 2; ++i)
#pragma unroll
    for (int ks = 0; ks < 2; ++ks) {
      int row = wid * 32 + i * 16 + l15;
      int ch = (ks * 4 + g) ^ (row & 7);
      qf[i][ks] = *(const bf16x8*)&Ps[row * 64 + ch * 8];
    }
  __syncthreads();  // all waves have Q; Ps reusable

  f32x4 oaccT[2][4] = {};
  float mrow[2] = {-1e30f, -1e30f}, lrow[2] = {0.f, 0.f};

  const int nt = 2 * qblk + 2;
  for (int t = 0; t < nt; ++t) {
    const int cur = t & 1;
    if (t + 1 < nt) {
      const int nb = cur ^ 1;
#pragma unroll
      for (int j = 0; j < 2; ++j) {
        int F = ((j * 4 + wid) << 10) + (lane << 4);
        int R = F >> 7;
        int cs = ((F >> 4) & 7) ^ (R & 7);
        gload_lds16(Kbase + (size_t)((t + 1) * 64 + R) * 64 + cs * 8, &Ks[nb][(j * 4 + wid) << 9]);
        gload_lds16(KTbase + (size_t)R * 2048 + (t + 1) * 64 + cs * 8, &KTs[nb][(j * 4 + wid) << 9]);
      }
    }
    // ---- S^T = K * Q^T  (rows = keys, cols = q); S is in log2 units (Q pre-scaled) ----
    f32x4 st[2][4] = {};
#pragma unroll
    for (int ks = 0; ks < 2; ++ks) {
      bf16x8 kf[4];
#pragma unroll
      for (int nf = 0; nf < 4; ++nf) {
        int row = nf * 16 + l15;
        int ch = (ks * 4 + g) ^ (row & 7);
        kf[nf] = *(const bf16x8*)&Ks[cur][row * 64 + ch * 8];
      }
      __builtin_amdgcn_s_setprio(1);
#pragma unroll
      for (int i = 0; i < 2; ++i)
#pragma unroll
        for (int nf = 0; nf < 4; ++nf)
          st[i][nf] = __builtin_amdgcn_mfma_f32_16x16x32_bf16(kf[nf], qf[i][ks], st[i][nf], 0, 0, 0);
      __builtin_amdgcn_s_setprio(0);
    }
    if (t >= 2 * qblk) {
#pragma unroll
      for (int i = 0; i < 2; ++i) {
        int qabs = q0 + wid * 32 + i * 16 + l15;
#pragma unroll
        for (int nf = 0; nf < 4; ++nf)
#pragma unroll
          for (int r = 0; r < 4; ++r) {
            int kabs = t * 64 + nf * 16 + 4 * g + r;
            if (kabs > qabs) st[i][nf][r] += -1e9f;
          }
      }
    }
    // ---- online softmax, exp2 domain, defer-max ----
#pragma unroll
    for (int i = 0; i < 2; ++i) {
      float pm = st[i][0][0];
#pragma unroll
      for (int nf = 0; nf < 4; ++nf)
#pragma unroll
        for (int r = 0; r < 4; ++r) pm = fmaxf(pm, st[i][nf][r]);
      pm = fmaxf(pm, __shfl_xor(pm, 16, 64));
      pm = fmaxf(pm, __shfl_xor(pm, 32, 64));
      if (!__all(pm <= mrow[i] + 8.f)) {
        float mnew = fmaxf(mrow[i], pm);
        float scale = fast_exp2(mrow[i] - mnew);
        mrow[i] = mnew;
        lrow[i] *= scale;
#pragma unroll
        for (int df = 0; df < 4; ++df)
#pragma unroll
          for (int r = 0; r < 4; ++r) oaccT[i][df][r] *= scale;
      }
      float rs = 0.f;
#pragma unroll
      for (int nf = 0; nf < 4; ++nf)
#pragma unroll
        for (int r = 0; r < 4; ++r) {
          float p = fast_exp2(st[i][nf][r] - mrow[i]);
          st[i][nf][r] = p;
          rs += p;
        }
      rs += __shfl_xor(rs, 16, 64);
      rs += __shfl_xor(rs, 32, 64);
      lrow[i] += rs;
    }
    // ---- write P rows (wave-private; 4 consecutive keys per frag -> b64 writes) ----
#pragma unroll
    for (int i = 0; i < 2; ++i) {
      int q = wid * 32 + i * 16 + l15;
#pragma unroll
      for (int nf = 0; nf < 4; ++nf) {
        int k0 = nf * 16 + 4 * g;
        int ch = (k0 >> 3) ^ (q & 7);
        ushort4 pk;
        pk.x = f2bf(st[i][nf][0]);
        pk.y = f2bf(st[i][nf][1]);
        pk.z = f2bf(st[i][nf][2]);
        pk.w = f2bf(st[i][nf][3]);
        *(ushort4*)&Ps[q * 64 + ch * 8 + (k0 & 7)] = pk;
      }
    }
    // no barrier: P rows are read only by the writing wave
    // ---- O^T += V^T * P^T  (rows = d, cols = q) ----
#pragma unroll
    for (int ks = 0; ks < 2; ++ks) {
      bf16x8 pf[2], vf[4];
#pragma unroll
      for (int i = 0; i < 2; ++i) {
        int row = wid * 32 + i * 16 + l15;
        int ch = (ks * 4 + g) ^ (row & 7);
        pf[i] = *(const bf16x8*)&Ps[row * 64 + ch * 8];
      }
#pragma unroll
      for (int df = 0; df < 4; ++df) {
        int row = df * 16 + l15;
        int ch = (ks * 4 + g) ^ (row & 7);
        vf[df] = *(const bf16x8*)&KTs[cur][row * 64 + ch * 8];
      }
      __builtin_amdgcn_s_setprio(1);
#pragma unroll
      for (int i = 0; i < 2; ++i)
#pragma unroll
        for (int df = 0; df < 4; ++df)
          oaccT[i][df] = __builtin_amdgcn_mfma_f32_16x16x32_bf16(vf[df], pf[i], oaccT[i][df], 0, 0, 0);
      __builtin_amdgcn_s_setprio(0);
    }
    __syncthreads();  // staging buffers for t+1 may now be overwritten
  }
  // ---- gated epilogue (O^T: lane holds q = lane&15, d = df*16 + 4g + r) ----
#pragma unroll
  for (int i = 0; i < 2; ++i) {
    float rl = 1.f / lrow[i];
    int qabs = q0 + wid * 32 + i * 16 + l15;
    size_t grow = (size_t)b * 2048 + qabs;
#pragma unroll
    for (int df = 0; df < 4; ++df) {
      int d0 = df * 16 + 4 * g;
      ushort4 gt = *(const ushort4*)&qgk[grow * 4608 + 2048 + h * 64 + d0];
      ushort4 o;
      float gate, gg;
      gate = bf2f(gt.x); gg = 1.f / (1.f + __expf(-gate)); o.x = f2bf(oaccT[i][df][0] * rl * gg);
      gate = bf2f(gt.y); gg = 1.f / (1.f + __expf(-gate)); o.y = f2bf(oaccT[i][df][1] * rl * gg);
      gate = bf2f(gt.z); gg = 1.f / (1.f + __expf(-gate)); o.z = f2bf(oaccT[i][df][2] * rl * gg);
      gate = bf2f(gt.w); gg = 1.f / (1.f + __expf(-gate)); o.w = f2bf(oaccT[i][df][3] * rl * gg);
      *(ushort4*)&attng[grow * 2048 + h * 64 + d0] = o;
    }
  }
}

extern "C" void kernel_launch(void* const* d_in, const int* in_sizes, int n_in,
                              void* d_out, int out_size, void* d_ws, size_t ws_size,
                              hipStream_t stream) {
  const float* hidden = (const float*)d_in[0];
  const float* cosT = (const float*)d_in[1];
  const float* sinT = (const float*)d_in[2];
  const float* wq = (const float*)d_in[4];
  const float* wk = (const float*)d_in[5];
  const float* wo = (const float*)d_in[7];
  char* ws = (char*)d_ws;
  unsigned short* hb16  = (unsigned short*)(ws + 0);          // 4096x2048 bf16
  unsigned short* wcatT = (unsigned short*)(ws + 16777216);   // 4608x2048 bf16 (wq^T rows 0..4095, wk^T rows 4096..4607)
  unsigned short* woT   = (unsigned short*)(ws + 35651584);   // 2048x2048 bf16
  unsigned short* qgk   = (unsigned short*)(ws + 44040192);   // 4096x4608 bf16 (q | gate | k)
  unsigned short* qrope = (unsigned short*)(ws + 81788928);   // [2][32][2048][64] bf16 (pre-scaled by log2e)
  unsigned short* krope = (unsigned short*)(ws + 98566144);   // [2][8][2048][64] bf16
  unsigned short* kTb   = (unsigned short*)(ws + 102760448);  // [2][8][64][2048] bf16
  unsigned short* attng = (unsigned short*)(ws + 106954752);  // 4096x2048 bf16

  conv_bf16<<<dim3(2048), dim3(256), 0, stream>>>(hidden, hb16, 2097152);
  tconv<<<dim3(128, 64), dim3(32, 8), 0, stream>>>(wq, wcatT, 4096, 0, 2048);
  tconv<<<dim3(16, 64), dim3(32, 8), 0, stream>>>(wk, wcatT, 512, 4096, 2048);
  tconv<<<dim3(64, 64), dim3(32, 8), 0, stream>>>(wo, woT, 2048, 0, 2048);
  gemm_bt<unsigned short><<<dim3(36, 32), dim3(256), 0, stream>>>(hb16, wcatT, qgk, 4096, 4608, 2048);
  rope_qk<<<dim3(1024, 40), dim3(256), 0, stream>>>(qgk, cosT, sinT, qrope, krope);
  ktrans<<<dim3(32, 16), dim3(256), 0, stream>>>(krope, kTb);
  attn_fused<<<dim3(64, 16), dim3(256), 0, stream>>>(qrope, krope, kTb, qgk, attng);
  gemm_bt<float><<<dim3(16, 32), dim3(256), 0, stream>>>(attng, woT, (float*)d_out, 4096, 2048, 2048);
}